// Round 3
// baseline (328.118 us; speedup 1.0000x reference)
//
#include <hip/hip_runtime.h>
#include <hip/hip_bf16.h>

typedef __bf16 bf16;
typedef __attribute__((ext_vector_type(8))) __bf16 bf16x8;
typedef __attribute__((ext_vector_type(4))) __bf16 bf16x4;
typedef __attribute__((ext_vector_type(4))) float f32x4;

// Problem constants
#define BB 2
#define SS 2048
#define HH 2048
#define NH 16
#define HD 128

#define GLOAD_LDS16(g, l)                                                  \
    __builtin_amdgcn_global_load_lds(                                      \
        (const __attribute__((address_space(1))) void*)(g),                \
        (__attribute__((address_space(3))) void*)(l), 16, 0, 0)

// ---------------------------------------------------------------------------
// fp32 -> bf16 cast, 4 elements/thread
// ---------------------------------------------------------------------------
__global__ __launch_bounds__(256) void cast_f32_bf16(const float* __restrict__ in,
                                                     bf16* __restrict__ out, int n4) {
    int i = blockIdx.x * 256 + threadIdx.x;
    if (i < n4) {
        f32x4 v = *reinterpret_cast<const f32x4*>(in + (size_t)i * 4);
        bf16x4 o;
        o[0] = (bf16)v[0]; o[1] = (bf16)v[1]; o[2] = (bf16)v[2]; o[3] = (bf16)v[3];
        *reinterpret_cast<bf16x4*>(out + (size_t)i * 4) = o;
    }
}

// ---------------------------------------------------------------------------
// GEMM (m97 structure): C[m,n] = sum_k A[m,k]*B[n,k], 128x128 tile, BK=64,
// linear LDS + global_load_lds width 16.
// EPI=0: N=6144 fused-QKV epilogue -> QKV[proj][b*NH+h][s][d] bf16
// EPI=1: fp32 row-major [M][N]
// ---------------------------------------------------------------------------
template <int EPI>
__global__ __launch_bounds__(256) void gemm_bt(const bf16* __restrict__ A,
                                               const bf16* __restrict__ B,
                                               float* __restrict__ Cf,
                                               bf16* __restrict__ Cb,
                                               int M, int N, int K) {
    __shared__ bf16 As[128 * 64];
    __shared__ bf16 Bs[128 * 64];
    const int tid = threadIdx.x;
    const int lane = tid & 63, wave = tid >> 6;
    const int l15 = lane & 15, lhi = lane >> 4;
    const int m0 = blockIdx.y * 128, n0 = blockIdx.x * 128;
    const int wm = (wave >> 1) * 64, wn = (wave & 1) * 64;
    const int lrow = lane >> 3;          // 0..7 within chunk
    const int lcol = (lane & 7) * 8;     // element col group

    f32x4 acc[4][4] = {};

    for (int k0 = 0; k0 < K; k0 += 64) {
#pragma unroll
        for (int j = 0; j < 4; ++j) {
            const int c = wave * 4 + j;              // chunk 0..15 (8 rows each)
            const int row = c * 8 + lrow;
            GLOAD_LDS16(&A[(size_t)(m0 + row) * K + k0 + lcol], &As[c * 512]);
            GLOAD_LDS16(&B[(size_t)(n0 + row) * K + k0 + lcol], &Bs[c * 512]);
        }
        __syncthreads();
#pragma unroll
        for (int ks = 0; ks < 2; ++ks) {
            bf16x8 af[4], bfr[4];
#pragma unroll
            for (int i = 0; i < 4; ++i)
                af[i] = *reinterpret_cast<const bf16x8*>(&As[(wm + i * 16 + l15) * 64 + ks * 32 + 8 * lhi]);
#pragma unroll
            for (int j = 0; j < 4; ++j)
                bfr[j] = *reinterpret_cast<const bf16x8*>(&Bs[(wn + j * 16 + l15) * 64 + ks * 32 + 8 * lhi]);
#pragma unroll
            for (int i = 0; i < 4; ++i)
#pragma unroll
                for (int j = 0; j < 4; ++j)
                    acc[i][j] = __builtin_amdgcn_mfma_f32_16x16x32_bf16(af[i], bfr[j], acc[i][j], 0, 0, 0);
        }
        __syncthreads();
    }

#pragma unroll
    for (int i = 0; i < 4; ++i)
#pragma unroll
        for (int j = 0; j < 4; ++j)
#pragma unroll
            for (int r = 0; r < 4; ++r) {
                int gm = m0 + wm + i * 16 + lhi * 4 + r;
                int gn = n0 + wn + j * 16 + l15;
                float v = acc[i][j][r];
                if (EPI == 0) {
                    int proj = gn >> 11;         // 0..2 (N=6144)
                    int n2 = gn & 2047;
                    int b = gm >> 11, s = gm & (SS - 1);
                    int h = n2 >> 7, d = n2 & (HD - 1);
                    size_t off = ((size_t)proj << 23) + ((((size_t)(b * NH + h)) * SS + s) << 7) + d;
                    Cb[off] = (bf16)v;
                } else {
                    Cf[(size_t)gm * N + gn] = v;
                }
            }
}

// ---------------------------------------------------------------------------
// Transpose V per head: Vh[head][s][d] -> Vt[head][d][s]
// ---------------------------------------------------------------------------
__global__ __launch_bounds__(256) void transpose_v(const bf16* __restrict__ Vh,
                                                   bf16* __restrict__ Vt) {
    __shared__ bf16 T[64 * 64];
    const int tid = threadIdx.x;
    const int s0 = blockIdx.x * 64, d0 = blockIdx.y * 64, head = blockIdx.z;
    const bf16* src = Vh + ((size_t)head * SS) * HD;
    bf16* dst = Vt + ((size_t)head * HD) * SS;

#pragma unroll
    for (int i = 0; i < 2; ++i) {
        int id = tid + i * 256;
        int r = id >> 3, c16 = id & 7;
        bf16x8 v = *reinterpret_cast<const bf16x8*>(&src[(size_t)(s0 + r) * HD + d0 + c16 * 8]);
        int sw = c16 ^ ((r ^ (r >> 3)) & 7);
        *reinterpret_cast<bf16x8*>((char*)T + r * 128 + sw * 16) = v;
    }
    __syncthreads();
#pragma unroll
    for (int i = 0; i < 2; ++i) {
        int id = tid + i * 256;
        int dr = id >> 3, sc8 = (id & 7) * 8;
        bf16x8 o;
#pragma unroll
        for (int j = 0; j < 8; ++j) {
            int r = sc8 + j;
            int sw = (dr >> 3) ^ ((r ^ (r >> 3)) & 7);
            o[j] = *reinterpret_cast<const bf16*>((char*)T + r * 128 + sw * 16 + (dr & 7) * 2);
        }
        *reinterpret_cast<bf16x8*>(&dst[(size_t)(d0 + dr) * SS + s0 + sc8]) = o;
    }
}

// ---------------------------------------------------------------------------
// RoPE (rotate_half), vectorized
// ---------------------------------------------------------------------------
__global__ __launch_bounds__(256) void rope_kernel(bf16* __restrict__ Qh, bf16* __restrict__ Kh,
                                                   const float* __restrict__ cosT,
                                                   const float* __restrict__ sinT) {
    int idx = blockIdx.x * 256 + threadIdx.x;
    int g = idx & 7;
    int s = (idx >> 3) & (SS - 1);
    int head = idx >> 14;
    int d0 = g * 8;
    size_t base = ((size_t)head * SS + s) * HD;
    f32x4 ca = *reinterpret_cast<const f32x4*>(&cosT[s * HD + d0]);
    f32x4 cb = *reinterpret_cast<const f32x4*>(&cosT[s * HD + d0 + 4]);
    f32x4 sa = *reinterpret_cast<const f32x4*>(&sinT[s * HD + d0]);
    f32x4 sb = *reinterpret_cast<const f32x4*>(&sinT[s * HD + d0 + 4]);
    bf16x8 ql = *reinterpret_cast<const bf16x8*>(&Qh[base + d0]);
    bf16x8 qh = *reinterpret_cast<const bf16x8*>(&Qh[base + 64 + d0]);
    bf16x8 kl = *reinterpret_cast<const bf16x8*>(&Kh[base + d0]);
    bf16x8 kh = *reinterpret_cast<const bf16x8*>(&Kh[base + 64 + d0]);
    bf16x8 qlo, qhi, klo, khi;
#pragma unroll
    for (int j = 0; j < 8; ++j) {
        float c = (j < 4) ? ca[j] : cb[j - 4];
        float sn = (j < 4) ? sa[j] : sb[j - 4];
        float q0 = (float)ql[j], q1 = (float)qh[j];
        float k0 = (float)kl[j], k1 = (float)kh[j];
        qlo[j] = (bf16)(q0 * c - q1 * sn);
        qhi[j] = (bf16)(q1 * c + q0 * sn);
        klo[j] = (bf16)(k0 * c - k1 * sn);
        khi[j] = (bf16)(k1 * c + k0 * sn);
    }
    *reinterpret_cast<bf16x8*>(&Qh[base + d0]) = qlo;
    *reinterpret_cast<bf16x8*>(&Qh[base + 64 + d0]) = qhi;
    *reinterpret_cast<bf16x8*>(&Kh[base + d0]) = klo;
    *reinterpret_cast<bf16x8*>(&Kh[base + 64 + d0]) = khi;
}

// ---------------------------------------------------------------------------
// Causal flash attention, load-balanced, K/V double-buffered, XOR-swizzled LDS,
// defer-max softmax. grid = 512, block = 256 (4 waves x 16 q-rows, QB=64).
// ---------------------------------------------------------------------------
__global__ __launch_bounds__(256) void attn_kernel(const bf16* __restrict__ Q,
                                                   const bf16* __restrict__ K,
                                                   const bf16* __restrict__ Vt,
                                                   bf16* __restrict__ Ob) {
    __shared__ bf16 Ks[2][64 * 128];   // 2 x 16 KB, swizzled
    __shared__ bf16 Vs[2][128 * 64];   // 2 x 16 KB, swizzled (d-major)
    __shared__ bf16 Ps[4][16][72];     // 9.2 KB

    const int tid = threadIdx.x, lane = tid & 63, wave = tid >> 6;
    const int l15 = lane & 15, lhi = lane >> 4;
    const int bid = blockIdx.x;
    const int orig = (bid & 7) * 64 + (bid >> 3);   // XCD swizzle (512 % 8 == 0)
    const int head = orig >> 4;
    const int pi = orig & 15;
    const int b = head >> 4, h = head & (NH - 1);
    const size_t hb = (size_t)head * SS * HD;
    const bf16* Vth = Vt + (size_t)head * HD * SS;
    const float cexp = 0.08838834764831845f * 1.4426950408889634f;  // scale*log2e
    const float THR = 62.0f;   // raw-score defer-max threshold (exp2 arg <= ~8)

#pragma unroll 1
    for (int part = 0; part < 2; ++part) {
        const int t = part ? (31 - pi) : pi;
        const int q0 = t * 64;
        const int qw = q0 + wave * 16;
        const int nkv = t + 1;

        bf16x8 qf[4];
#pragma unroll
        for (int ks = 0; ks < 4; ++ks)
            qf[ks] = *reinterpret_cast<const bf16x8*>(
                &Q[hb + (size_t)(qw + l15) * HD + ks * 32 + 8 * lhi]);

        f32x4 oacc[8] = {};
        float Mr[4], Lp[4];
#pragma unroll
        for (int r = 0; r < 4; ++r) { Mr[r] = -INFINITY; Lp[r] = 0.f; }

        bf16x8 kr[4], vr[4];
        // ---- prologue: stage tile 0 ----
#pragma unroll
        for (int i = 0; i < 4; ++i) {
            int id = tid + i * 256;
            kr[i] = *reinterpret_cast<const bf16x8*>(&K[hb + (size_t)(id >> 4) * HD + (id & 15) * 8]);
            vr[i] = *reinterpret_cast<const bf16x8*>(&Vth[(size_t)(id >> 3) * SS + (id & 7) * 8]);
        }
#pragma unroll
        for (int i = 0; i < 4; ++i) {
            int id = tid + i * 256;
            int krow = id >> 4, kc = id & 15;
            *reinterpret_cast<bf16x8*>((char*)Ks[0] + ((krow * 256 + kc * 16) ^ ((krow & 7) << 4))) = kr[i];
            int vrow = id >> 3, vc = id & 7;
            *reinterpret_cast<bf16x8*>((char*)Vs[0] + ((vrow * 128 + vc * 16) ^ ((vrow & 7) << 4))) = vr[i];
        }
        __syncthreads();

        for (int it = 0; it < nkv; ++it) {
            const int cur = it & 1;
            const bool pre = (it + 1 < nkv);
            if (pre) {
                const int kv0 = (it + 1) * 64;
#pragma unroll
                for (int i = 0; i < 4; ++i) {
                    int id = tid + i * 256;
                    kr[i] = *reinterpret_cast<const bf16x8*>(&K[hb + (size_t)(kv0 + (id >> 4)) * HD + (id & 15) * 8]);
                    vr[i] = *reinterpret_cast<const bf16x8*>(&Vth[(size_t)(id >> 3) * SS + kv0 + (id & 7) * 8]);
                }
            }

            // ---- S = Q K^T ----
            f32x4 sf[4] = {};
#pragma unroll
            for (int ks = 0; ks < 4; ++ks) {
#pragma unroll
                for (int ne = 0; ne < 4; ++ne) {
                    int row = ne * 16 + l15;
                    bf16x8 kf = *reinterpret_cast<const bf16x8*>(
                        (const char*)Ks[cur] + ((row * 256 + (ks * 4 + lhi) * 16) ^ ((row & 7) << 4)));
                    sf[ne] = __builtin_amdgcn_mfma_f32_16x16x32_bf16(qf[ks], kf, sf[ne], 0, 0, 0);
                }
            }

            // causal mask only on the diagonal tile
            if (it == nkv - 1) {
#pragma unroll
                for (int ne = 0; ne < 4; ++ne)
#pragma unroll
                    for (int r = 0; r < 4; ++r) {
                        int gq = qw + lhi * 4 + r;
                        int gk = it * 64 + ne * 16 + l15;
                        if (gk > gq) sf[ne][r] = -INFINITY;
                    }
            }

            // ---- defer-max online softmax ----
            float lm[4];
#pragma unroll
            for (int r = 0; r < 4; ++r)
                lm[r] = fmaxf(fmaxf(sf[0][r], sf[1][r]), fmaxf(sf[2][r], sf[3][r]));
            bool need = (lm[0] > Mr[0] + THR) || (lm[1] > Mr[1] + THR) ||
                        (lm[2] > Mr[2] + THR) || (lm[3] > Mr[3] + THR);
            if (__any(need)) {
                float rmax[4] = {lm[0], lm[1], lm[2], lm[3]};
#pragma unroll
                for (int m = 1; m < 16; m <<= 1)
#pragma unroll
                    for (int r = 0; r < 4; ++r)
                        rmax[r] = fmaxf(rmax[r], __shfl_xor(rmax[r], m));
#pragma unroll
                for (int r = 0; r < 4; ++r) {
                    float nM = fmaxf(Mr[r], rmax[r]);
                    float scf = __builtin_amdgcn_exp2f((Mr[r] - nM) * cexp);
                    Mr[r] = nM;
                    Lp[r] *= scf;
#pragma unroll
                    for (int nf = 0; nf < 8; ++nf) oacc[nf][r] *= scf;
                }
            }
#pragma unroll
            for (int ne = 0; ne < 4; ++ne)
#pragma unroll
                for (int r = 0; r < 4; ++r) {
                    float p = __builtin_amdgcn_exp2f((sf[ne][r] - Mr[r]) * cexp);
                    Lp[r] += p;
                    Ps[wave][lhi * 4 + r][ne * 16 + l15] = (bf16)p;
                }

            // ---- O += P @ V ----
#pragma unroll
            for (int ks = 0; ks < 2; ++ks) {
                bf16x8 pa = *reinterpret_cast<const bf16x8*>(&Ps[wave][l15][ks * 32 + 8 * lhi]);
#pragma unroll
                for (int nf = 0; nf < 8; ++nf) {
                    int row = nf * 16 + l15;
                    bf16x8 vb = *reinterpret_cast<const bf16x8*>(
                        (const char*)Vs[cur] + ((row * 128 + (ks * 4 + lhi) * 16) ^ ((row & 7) << 4)));
                    oacc[nf] = __builtin_amdgcn_mfma_f32_16x16x32_bf16(pa, vb, oacc[nf], 0, 0, 0);
                }
            }

            // ---- write next tile into the other buffer (T14 write-late) ----
            if (pre) {
#pragma unroll
                for (int i = 0; i < 4; ++i) {
                    int id = tid + i * 256;
                    int krow = id >> 4, kc = id & 15;
                    *reinterpret_cast<bf16x8*>((char*)Ks[cur ^ 1] + ((krow * 256 + kc * 16) ^ ((krow & 7) << 4))) = kr[i];
                    int vrow = id >> 3, vc = id & 7;
                    *reinterpret_cast<bf16x8*>((char*)Vs[cur ^ 1] + ((vrow * 128 + vc * 16) ^ ((vrow & 7) << 4))) = vr[i];
                }
            }
            __syncthreads();
        }

        // ---- final L reduce (once per part) + epilogue ----
#pragma unroll
        for (int m = 1; m < 16; m <<= 1)
#pragma unroll
            for (int r = 0; r < 4; ++r)
                Lp[r] += __shfl_xor(Lp[r], m);
        float inv[4];
#pragma unroll
        for (int r = 0; r < 4; ++r) inv[r] = 1.f / Lp[r];
#pragma unroll
        for (int nf = 0; nf < 8; ++nf)
#pragma unroll
            for (int r = 0; r < 4; ++r) {
                int s = qw + lhi * 4 + r;
                int d = nf * 16 + l15;
                Ob[((size_t)(b * SS + s)) * HH + h * HD + d] = (bf16)(oacc[nf][r] * inv[r]);
            }
    }
}

// ---------------------------------------------------------------------------
extern "C" void kernel_launch(void* const* d_in, const int* in_sizes, int n_in,
                              void* d_out, int out_size, void* d_ws, size_t ws_size,
                              hipStream_t stream) {
    const float* hs   = (const float*)d_in[0];
    const float* cosT = (const float*)d_in[2];
    const float* sinT = (const float*)d_in[3];
    const float* Wq   = (const float*)d_in[4];
    const float* Wk   = (const float*)d_in[5];
    const float* Wv   = (const float*)d_in[6];
    const float* Wo   = (const float*)d_in[7];
    float* out = (float*)d_out;

    char* w = (char*)d_ws;
    auto alloc = [&](size_t bytes) {
        char* p = w;
        w += (bytes + 255) & ~(size_t)255;
        return p;
    };
    const size_t XE = (size_t)BB * SS * HH;       // 8388608 elements
    const size_t WE = (size_t)HH * HH;
    bf16* Xb   = (bf16*)alloc(XE * 2);
    bf16* Wqkv = (bf16*)alloc(3 * WE * 2);        // contiguous [3*H][H]
    bf16* Wob  = (bf16*)alloc(WE * 2);
    bf16* QKV  = (bf16*)alloc(3 * XE * 2);        // [3][B*NH][S][HD]
    bf16* Vtg  = (bf16*)alloc(XE * 2);
    bf16* Ob   = (bf16*)alloc(XE * 2);

    const int M = BB * SS;  // 4096
    bf16* Qh = QKV;
    bf16* Kh = QKV + XE;
    bf16* Vh = QKV + 2 * XE;

    cast_f32_bf16<<<(int)(XE / 4 + 255) / 256, 256, 0, stream>>>(hs, Xb, (int)(XE / 4));
    cast_f32_bf16<<<(int)(WE / 4 + 255) / 256, 256, 0, stream>>>(Wq, Wqkv, (int)(WE / 4));
    cast_f32_bf16<<<(int)(WE / 4 + 255) / 256, 256, 0, stream>>>(Wk, Wqkv + WE, (int)(WE / 4));
    cast_f32_bf16<<<(int)(WE / 4 + 255) / 256, 256, 0, stream>>>(Wv, Wqkv + 2 * WE, (int)(WE / 4));
    cast_f32_bf16<<<(int)(WE / 4 + 255) / 256, 256, 0, stream>>>(Wo, Wob, (int)(WE / 4));

    // fused QKV projection: M=4096, N=6144, K=2048
    dim3 qgrid(3 * HH / 128, M / 128);
    gemm_bt<0><<<qgrid, 256, 0, stream>>>(Xb, Wqkv, nullptr, QKV, M, 3 * HH, HH);

    rope_kernel<<<(BB * NH * SS * 8) / 256, 256, 0, stream>>>(Qh, Kh, cosT, sinT);

    dim3 tgrid(SS / 64, HD / 64, BB * NH);
    transpose_v<<<tgrid, 256, 0, stream>>>(Vh, Vtg);

    attn_kernel<<<512, 256, 0, stream>>>(Qh, Kh, Vtg, Ob);

    dim3 ogrid(HH / 128, M / 128);
    gemm_bt<1><<<ogrid, 256, 0, stream>>>(Ob, Wob, out, nullptr, M, HH, HH);
}

// Round 4
// 320.108 us; speedup vs baseline: 1.0250x; 1.0250x over previous
//
#include <hip/hip_runtime.h>
#include <hip/hip_bf16.h>

typedef __bf16 bf16;
typedef __attribute__((ext_vector_type(8))) __bf16 bf16x8;
typedef __attribute__((ext_vector_type(4))) __bf16 bf16x4;
typedef __attribute__((ext_vector_type(4))) float f32x4;

// Problem constants
#define BB 2
#define SS 2048
#define HH 2048
#define NH 16
#define HD 128

#define GLOAD_LDS16(g, l)                                                  \
    __builtin_amdgcn_global_load_lds(                                      \
        (const __attribute__((address_space(1))) void*)(g),                \
        (__attribute__((address_space(3))) void*)(l), 16, 0, 0)

// ---------------------------------------------------------------------------
// fp32 -> bf16 cast, 4 elements/thread
// ---------------------------------------------------------------------------
__global__ __launch_bounds__(256) void cast_f32_bf16(const float* __restrict__ in,
                                                     bf16* __restrict__ out, int n4) {
    int i = blockIdx.x * 256 + threadIdx.x;
    if (i < n4) {
        f32x4 v = *reinterpret_cast<const f32x4*>(in + (size_t)i * 4);
        bf16x4 o;
        o[0] = (bf16)v[0]; o[1] = (bf16)v[1]; o[2] = (bf16)v[2]; o[3] = (bf16)v[3];
        *reinterpret_cast<bf16x4*>(out + (size_t)i * 4) = o;
    }
}

// ---------------------------------------------------------------------------
// 256x256-tile 8-phase GEMM (T2+T3+T4+T5), QKV epilogue.
// C[m,n] = sum_k A[m,k]*B[n,k]. 512 threads = 8 waves (2 wr x 4 wc).
// Per wave: 128x64 output = acc[8][4]. BK=64, 2-K-tile LDS double buffer.
// st_16x32 swizzle: T ^= ((T>>10)&1)<<5 (both-sides: pre-swizzled global src
// for linear global_load_lds dest + swizzled ds_read).
// Phases per K-tile: q0=(0,0) q1=(0,1) q2=(1,1) q3=(1,0).
// Staging stream at tile t: q0->B0(t+1) q1->A1(t+1) q2->A0(t+2) q3->B1(t+2);
// boundary s_waitcnt vmcnt(4) (= 2 half-tiles in flight), vmcnt(0) only
// before the last K-tile.
// ---------------------------------------------------------------------------
__global__ __launch_bounds__(512, 2) void gemm256_qkv(const bf16* __restrict__ A,
                                                      const bf16* __restrict__ B,
                                                      bf16* __restrict__ Cb,
                                                      int M, int N, int K) {
    __shared__ bf16 LA[2][256 * 64];
    __shared__ bf16 LB[2][256 * 64];
    const int tid = threadIdx.x, lane = tid & 63, wave = tid >> 6;
    const int l15 = lane & 15, lhi = lane >> 4;
    const int wr = wave >> 2, wc = wave & 3;
    const int NBX = N >> 8;
    const int cpx = gridDim.x >> 3;                        // nwg % 8 == 0
    const int wg = (blockIdx.x & 7) * cpx + (blockIdx.x >> 3);
    const int m0 = (wg / NBX) * 256, n0 = (wg % NBX) * 256;
    const int NK = K >> 6;
    const int xor5 = (l15 & 8) << 2;                       // read-side swizzle bit

    // stage A half h (rows {h*64..h*64+63} U {128+h*64..}) of K-tile t -> LA[buf]
    auto stageA = [&](int buf, int t, int h) {
        const int k0 = t << 6;
#pragma unroll
        for (int j = 0; j < 2; ++j) {
            int Xw = ((j * 128 + h * 64) << 7) + (wave << 10);   // wave-uniform LDS byte
            int X = Xw + lane * 16;
            int T = X ^ (((X >> 10) & 1) << 5);                  // inverse-swizzled source
            GLOAD_LDS16(&A[(size_t)(m0 + (T >> 7)) * K + k0 + ((T & 127) >> 1)],
                        (char*)LA[buf] + Xw);
        }
    };
    // stage B half h (rows with (row>>5)&1 == h) of K-tile t -> LB[buf]
    auto stageB = [&](int buf, int t, int h) {
        const int k0 = t << 6;
#pragma unroll
        for (int j = 0; j < 2; ++j) {
            int base_row = h * 32 + (2 * j + (wave >> 2)) * 64;
            int Xw = (base_row << 7) + ((wave & 3) << 10);
            int X = Xw + lane * 16;
            int T = X ^ (((X >> 10) & 1) << 5);
            GLOAD_LDS16(&B[(size_t)(n0 + (T >> 7)) * K + k0 + ((T & 127) >> 1)],
                        (char*)LB[buf] + Xw);
        }
    };

    f32x4 acc[8][4] = {};

    // prologue: tile0 all 4 halves + A0(1), B1(1)  (6 halves = 12 loads)
    stageA(0, 0, 0); stageB(0, 0, 0); stageB(0, 0, 1); stageA(0, 0, 1);
    stageA(1, 1, 0); stageB(1, 1, 1);
    asm volatile("s_waitcnt vmcnt(4)" ::: "memory");       // tile0 landed
    __builtin_amdgcn_s_barrier();

    bf16x8 af[4][2], bv0[2][2], bv1[2][2];

#pragma unroll 1
    for (int t = 0; t < NK; ++t) {
        const int buf = t & 1;
        char* lA = (char*)LA[buf];
        char* lB = (char*)LB[buf];

        // ===== phase q0: quadrant (qm=0,qn=0); read A0(8)+B0(4); stage B0(t+1)
#pragma unroll
        for (int f = 0; f < 4; ++f)
#pragma unroll
            for (int ks = 0; ks < 2; ++ks) {
                int T = ((wr * 128 + f * 16 + l15) << 7) + ks * 64 + lhi * 16;
                af[f][ks] = *reinterpret_cast<const bf16x8*>(lA + (T ^ xor5));
            }
#pragma unroll
        for (int g = 0; g < 2; ++g)
#pragma unroll
            for (int ks = 0; ks < 2; ++ks) {
                int T = ((wc * 64 + g * 16 + l15) << 7) + ks * 64 + lhi * 16;
                bv0[g][ks] = *reinterpret_cast<const bf16x8*>(lB + (T ^ xor5));
            }
        if (t + 1 < NK) stageB(buf ^ 1, t + 1, 0);
        __builtin_amdgcn_s_barrier();
        asm volatile("s_waitcnt lgkmcnt(0)" ::: "memory");
        __builtin_amdgcn_s_setprio(1);
#pragma unroll
        for (int f = 0; f < 4; ++f)
#pragma unroll
            for (int g = 0; g < 2; ++g)
#pragma unroll
                for (int ks = 0; ks < 2; ++ks)
                    acc[f][g] = __builtin_amdgcn_mfma_f32_16x16x32_bf16(af[f][ks], bv0[g][ks], acc[f][g], 0, 0, 0);
        __builtin_amdgcn_s_setprio(0);
        __builtin_amdgcn_s_barrier();

        // ===== phase q1: quadrant (0,1); read B1(4); reuse af; stage A1(t+1)
#pragma unroll
        for (int g = 0; g < 2; ++g)
#pragma unroll
            for (int ks = 0; ks < 2; ++ks) {
                int T = ((wc * 64 + 32 + g * 16 + l15) << 7) + ks * 64 + lhi * 16;
                bv1[g][ks] = *reinterpret_cast<const bf16x8*>(lB + (T ^ xor5));
            }
        if (t + 1 < NK) stageA(buf ^ 1, t + 1, 1);
        __builtin_amdgcn_s_barrier();
        asm volatile("s_waitcnt lgkmcnt(0)" ::: "memory");
        __builtin_amdgcn_s_setprio(1);
#pragma unroll
        for (int f = 0; f < 4; ++f)
#pragma unroll
            for (int g = 0; g < 2; ++g)
#pragma unroll
                for (int ks = 0; ks < 2; ++ks)
                    acc[f][2 + g] = __builtin_amdgcn_mfma_f32_16x16x32_bf16(af[f][ks], bv1[g][ks], acc[f][2 + g], 0, 0, 0);
        __builtin_amdgcn_s_setprio(0);
        __builtin_amdgcn_s_barrier();

        // ===== phase q2: quadrant (1,1); read A1(8) (overwrite af); reuse bv1; stage A0(t+2)
#pragma unroll
        for (int f = 0; f < 4; ++f)
#pragma unroll
            for (int ks = 0; ks < 2; ++ks) {
                int T = ((wr * 128 + 64 + f * 16 + l15) << 7) + ks * 64 + lhi * 16;
                af[f][ks] = *reinterpret_cast<const bf16x8*>(lA + (T ^ xor5));
            }
        if (t + 2 < NK) stageA(buf, t + 2, 0);
        __builtin_amdgcn_s_barrier();
        asm volatile("s_waitcnt lgkmcnt(0)" ::: "memory");
        __builtin_amdgcn_s_setprio(1);
#pragma unroll
        for (int f = 0; f < 4; ++f)
#pragma unroll
            for (int g = 0; g < 2; ++g)
#pragma unroll
                for (int ks = 0; ks < 2; ++ks)
                    acc[4 + f][2 + g] = __builtin_amdgcn_mfma_f32_16x16x32_bf16(af[f][ks], bv1[g][ks], acc[4 + f][2 + g], 0, 0, 0);
        __builtin_amdgcn_s_setprio(0);
        __builtin_amdgcn_s_barrier();

        // ===== phase q3: quadrant (1,0); no reads (af=A1, bv0 live); stage B1(t+2)
        if (t + 2 < NK) stageB(buf, t + 2, 1);
        __builtin_amdgcn_s_barrier();
        __builtin_amdgcn_s_setprio(1);
#pragma unroll
        for (int f = 0; f < 4; ++f)
#pragma unroll
            for (int g = 0; g < 2; ++g)
#pragma unroll
                for (int ks = 0; ks < 2; ++ks)
                    acc[4 + f][g] = __builtin_amdgcn_mfma_f32_16x16x32_bf16(af[f][ks], bv0[g][ks], acc[4 + f][g], 0, 0, 0);
        __builtin_amdgcn_s_setprio(0);
        // K-tile boundary: counted vmcnt (never 0 except before last tile)
        if (t + 2 == NK) {
            asm volatile("s_waitcnt vmcnt(0)" ::: "memory");
        } else if (t + 1 < NK) {
            asm volatile("s_waitcnt vmcnt(4)" ::: "memory");
        }
        __builtin_amdgcn_s_barrier();
    }

    // epilogue: per-head scatter [proj][b*NH+h][s][d] bf16
#pragma unroll
    for (int mf = 0; mf < 8; ++mf)
#pragma unroll
        for (int nf = 0; nf < 4; ++nf)
#pragma unroll
            for (int r = 0; r < 4; ++r) {
                int gm = m0 + wr * 128 + mf * 16 + lhi * 4 + r;
                int gn = n0 + wc * 64 + nf * 16 + l15;
                int proj = gn >> 11, n2 = gn & 2047;
                int b = gm >> 11, s = gm & (SS - 1);
                int h = n2 >> 7, d = n2 & (HD - 1);
                Cb[((size_t)proj << 23) + ((((size_t)(b * NH + h)) * SS + s) << 7) + d] =
                    (bf16)acc[mf][nf][r];
            }
}

// ---------------------------------------------------------------------------
// 128x128 GEMM (m97 structure), fp32 row-major epilogue (out projection)
// ---------------------------------------------------------------------------
__global__ __launch_bounds__(256) void gemm_bt(const bf16* __restrict__ A,
                                               const bf16* __restrict__ B,
                                               float* __restrict__ Cf,
                                               int M, int N, int K) {
    __shared__ bf16 As[128 * 64];
    __shared__ bf16 Bs[128 * 64];
    const int tid = threadIdx.x;
    const int lane = tid & 63, wave = tid >> 6;
    const int l15 = lane & 15, lhi = lane >> 4;
    const int m0 = blockIdx.y * 128, n0 = blockIdx.x * 128;
    const int wm = (wave >> 1) * 64, wn = (wave & 1) * 64;
    const int lrow = lane >> 3;
    const int lcol = (lane & 7) * 8;

    f32x4 acc[4][4] = {};

    for (int k0 = 0; k0 < K; k0 += 64) {
#pragma unroll
        for (int j = 0; j < 4; ++j) {
            const int c = wave * 4 + j;
            const int row = c * 8 + lrow;
            GLOAD_LDS16(&A[(size_t)(m0 + row) * K + k0 + lcol], &As[c * 512]);
            GLOAD_LDS16(&B[(size_t)(n0 + row) * K + k0 + lcol], &Bs[c * 512]);
        }
        __syncthreads();
#pragma unroll
        for (int ks = 0; ks < 2; ++ks) {
            bf16x8 af[4], bfr[4];
#pragma unroll
            for (int i = 0; i < 4; ++i)
                af[i] = *reinterpret_cast<const bf16x8*>(&As[(wm + i * 16 + l15) * 64 + ks * 32 + 8 * lhi]);
#pragma unroll
            for (int j = 0; j < 4; ++j)
                bfr[j] = *reinterpret_cast<const bf16x8*>(&Bs[(wn + j * 16 + l15) * 64 + ks * 32 + 8 * lhi]);
#pragma unroll
            for (int i = 0; i < 4; ++i)
#pragma unroll
                for (int j = 0; j < 4; ++j)
                    acc[i][j] = __builtin_amdgcn_mfma_f32_16x16x32_bf16(af[i], bfr[j], acc[i][j], 0, 0, 0);
        }
        __syncthreads();
    }

#pragma unroll
    for (int i = 0; i < 4; ++i)
#pragma unroll
        for (int j = 0; j < 4; ++j)
#pragma unroll
            for (int r = 0; r < 4; ++r) {
                int gm = m0 + wm + i * 16 + lhi * 4 + r;
                int gn = n0 + wn + j * 16 + l15;
                Cf[(size_t)gm * N + gn] = acc[i][j][r];
            }
}

// ---------------------------------------------------------------------------
// Transpose V per head: Vh[head][s][d] -> Vt[head][d][s]
// ---------------------------------------------------------------------------
__global__ __launch_bounds__(256) void transpose_v(const bf16* __restrict__ Vh,
                                                   bf16* __restrict__ Vt) {
    __shared__ bf16 T[64 * 64];
    const int tid = threadIdx.x;
    const int s0 = blockIdx.x * 64, d0 = blockIdx.y * 64, head = blockIdx.z;
    const bf16* src = Vh + ((size_t)head * SS) * HD;
    bf16* dst = Vt + ((size_t)head * HD) * SS;

#pragma unroll
    for (int i = 0; i < 2; ++i) {
        int id = tid + i * 256;
        int r = id >> 3, c16 = id & 7;
        bf16x8 v = *reinterpret_cast<const bf16x8*>(&src[(size_t)(s0 + r) * HD + d0 + c16 * 8]);
        int sw = c16 ^ ((r ^ (r >> 3)) & 7);
        *reinterpret_cast<bf16x8*>((char*)T + r * 128 + sw * 16) = v;
    }
    __syncthreads();
#pragma unroll
    for (int i = 0; i < 2; ++i) {
        int id = tid + i * 256;
        int dr = id >> 3, sc8 = (id & 7) * 8;
        bf16x8 o;
#pragma unroll
        for (int j = 0; j < 8; ++j) {
            int r = sc8 + j;
            int sw = (dr >> 3) ^ ((r ^ (r >> 3)) & 7);
            o[j] = *reinterpret_cast<const bf16*>((char*)T + r * 128 + sw * 16 + (dr & 7) * 2);
        }
        *reinterpret_cast<bf16x8*>(&dst[(size_t)(d0 + dr) * SS + s0 + sc8]) = o;
    }
}

// ---------------------------------------------------------------------------
// RoPE (rotate_half), vectorized
// ---------------------------------------------------------------------------
__global__ __launch_bounds__(256) void rope_kernel(bf16* __restrict__ Qh, bf16* __restrict__ Kh,
                                                   const float* __restrict__ cosT,
                                                   const float* __restrict__ sinT) {
    int idx = blockIdx.x * 256 + threadIdx.x;
    int g = idx & 7;
    int s = (idx >> 3) & (SS - 1);
    int head = idx >> 14;
    int d0 = g * 8;
    size_t base = ((size_t)head * SS + s) * HD;
    f32x4 ca = *reinterpret_cast<const f32x4*>(&cosT[s * HD + d0]);
    f32x4 cb = *reinterpret_cast<const f32x4*>(&cosT[s * HD + d0 + 4]);
    f32x4 sa = *reinterpret_cast<const f32x4*>(&sinT[s * HD + d0]);
    f32x4 sb = *reinterpret_cast<const f32x4*>(&sinT[s * HD + d0 + 4]);
    bf16x8 ql = *reinterpret_cast<const bf16x8*>(&Qh[base + d0]);
    bf16x8 qh = *reinterpret_cast<const bf16x8*>(&Qh[base + 64 + d0]);
    bf16x8 kl = *reinterpret_cast<const bf16x8*>(&Kh[base + d0]);
    bf16x8 kh = *reinterpret_cast<const bf16x8*>(&Kh[base + 64 + d0]);
    bf16x8 qlo, qhi, klo, khi;
#pragma unroll
    for (int j = 0; j < 8; ++j) {
        float c = (j < 4) ? ca[j] : cb[j - 4];
        float sn = (j < 4) ? sa[j] : sb[j - 4];
        float q0 = (float)ql[j], q1 = (float)qh[j];
        float k0 = (float)kl[j], k1 = (float)kh[j];
        qlo[j] = (bf16)(q0 * c - q1 * sn);
        qhi[j] = (bf16)(q1 * c + q0 * sn);
        klo[j] = (bf16)(k0 * c - k1 * sn);
        khi[j] = (bf16)(k1 * c + k0 * sn);
    }
    *reinterpret_cast<bf16x8*>(&Qh[base + d0]) = qlo;
    *reinterpret_cast<bf16x8*>(&Qh[base + 64 + d0]) = qhi;
    *reinterpret_cast<bf16x8*>(&Kh[base + d0]) = klo;
    *reinterpret_cast<bf16x8*>(&Kh[base + 64 + d0]) = khi;
}

// ---------------------------------------------------------------------------
// Causal flash attention, load-balanced, K/V double-buffered, XOR-swizzled LDS,
// defer-max softmax. grid = 512, block = 256 (4 waves x 16 q-rows, QB=64).
// ---------------------------------------------------------------------------
__global__ __launch_bounds__(256) void attn_kernel(const bf16* __restrict__ Q,
                                                   const bf16* __restrict__ K,
                                                   const bf16* __restrict__ Vt,
                                                   bf16* __restrict__ Ob) {
    __shared__ bf16 Ks[2][64 * 128];
    __shared__ bf16 Vs[2][128 * 64];
    __shared__ bf16 Ps[4][16][72];

    const int tid = threadIdx.x, lane = tid & 63, wave = tid >> 6;
    const int l15 = lane & 15, lhi = lane >> 4;
    const int bid = blockIdx.x;
    const int orig = (bid & 7) * 64 + (bid >> 3);
    const int head = orig >> 4;
    const int pi = orig & 15;
    const int b = head >> 4, h = head & (NH - 1);
    const size_t hb = (size_t)head * SS * HD;
    const bf16* Vth = Vt + (size_t)head * HD * SS;
    const float cexp = 0.08838834764831845f * 1.4426950408889634f;
    const float THR = 62.0f;

#pragma unroll 1
    for (int part = 0; part < 2; ++part) {
        const int t = part ? (31 - pi) : pi;
        const int q0 = t * 64;
        const int qw = q0 + wave * 16;
        const int nkv = t + 1;

        bf16x8 qf[4];
#pragma unroll
        for (int ks = 0; ks < 4; ++ks)
            qf[ks] = *reinterpret_cast<const bf16x8*>(
                &Q[hb + (size_t)(qw + l15) * HD + ks * 32 + 8 * lhi]);

        f32x4 oacc[8] = {};
        float Mr[4], Lp[4];
#pragma unroll
        for (int r = 0; r < 4; ++r) { Mr[r] = -INFINITY; Lp[r] = 0.f; }

        bf16x8 kr[4], vr[4];
#pragma unroll
        for (int i = 0; i < 4; ++i) {
            int id = tid + i * 256;
            kr[i] = *reinterpret_cast<const bf16x8*>(&K[hb + (size_t)(id >> 4) * HD + (id & 15) * 8]);
            vr[i] = *reinterpret_cast<const bf16x8*>(&Vth[(size_t)(id >> 3) * SS + (id & 7) * 8]);
        }
#pragma unroll
        for (int i = 0; i < 4; ++i) {
            int id = tid + i * 256;
            int krow = id >> 4, kc = id & 15;
            *reinterpret_cast<bf16x8*>((char*)Ks[0] + ((krow * 256 + kc * 16) ^ ((krow & 7) << 4))) = kr[i];
            int vrow = id >> 3, vc = id & 7;
            *reinterpret_cast<bf16x8*>((char*)Vs[0] + ((vrow * 128 + vc * 16) ^ ((vrow & 7) << 4))) = vr[i];
        }
        __syncthreads();

        for (int it = 0; it < nkv; ++it) {
            const int cur = it & 1;
            const bool pre = (it + 1 < nkv);
            if (pre) {
                const int kv0 = (it + 1) * 64;
#pragma unroll
                for (int i = 0; i < 4; ++i) {
                    int id = tid + i * 256;
                    kr[i] = *reinterpret_cast<const bf16x8*>(&K[hb + (size_t)(kv0 + (id >> 4)) * HD + (id & 15) * 8]);
                    vr[i] = *reinterpret_cast<const bf16x8*>(&Vth[(size_t)(id >> 3) * SS + kv0 + (id & 7) * 8]);
                }
            }

            f32x4 sf[4] = {};
#pragma unroll
            for (int ks = 0; ks < 4; ++ks) {
#pragma unroll
                for (int ne = 0; ne < 4; ++ne) {
                    int row = ne * 16 + l15;
                    bf16x8 kf = *reinterpret_cast<const bf16x8*>(
                        (const char*)Ks[cur] + ((row * 256 + (ks * 4 + lhi) * 16) ^ ((row & 7) << 4)));
                    sf[ne] = __builtin_amdgcn_mfma_f32_16x16x32_bf16(qf[ks], kf, sf[ne], 0, 0, 0);
                }
            }

            if (it == nkv - 1) {
#pragma unroll
                for (int ne = 0; ne < 4; ++ne)
#pragma unroll
                    for (int r = 0; r < 4; ++r) {
                        int gq = qw + lhi * 4 + r;
                        int gk = it * 64 + ne * 16 + l15;
                        if (gk > gq) sf[ne][r] = -INFINITY;
                    }
            }

            float lm[4];
#pragma unroll
            for (int r = 0; r < 4; ++r)
                lm[r] = fmaxf(fmaxf(sf[0][r], sf[1][r]), fmaxf(sf[2][r], sf[3][r]));
            bool need = (lm[0] > Mr[0] + THR) || (lm[1] > Mr[1] + THR) ||
                        (lm[2] > Mr[2] + THR) || (lm[3] > Mr[3] + THR);
            if (__any(need)) {
                float rmax[4] = {lm[0], lm[1], lm[2], lm[3]};
#pragma unroll
                for (int m = 1; m < 16; m <<= 1)
#pragma unroll
                    for (int r = 0; r < 4; ++r)
                        rmax[r] = fmaxf(rmax[r], __shfl_xor(rmax[r], m));
#pragma unroll
                for (int r = 0; r < 4; ++r) {
                    float nM = fmaxf(Mr[r], rmax[r]);
                    float scf = __builtin_amdgcn_exp2f((Mr[r] - nM) * cexp);
                    Mr[r] = nM;
                    Lp[r] *= scf;
#pragma unroll
                    for (int nf = 0; nf < 8; ++nf) oacc[nf][r] *= scf;
                }
            }
#pragma unroll
            for (int ne = 0; ne < 4; ++ne)
#pragma unroll
                for (int r = 0; r < 4; ++r) {
                    float p = __builtin_amdgcn_exp2f((sf[ne][r] - Mr[r]) * cexp);
                    Lp[r] += p;
                    Ps[wave][lhi * 4 + r][ne * 16 + l15] = (bf16)p;
                }

#pragma unroll
            for (int ks = 0; ks < 2; ++ks) {
                bf16x8 pa = *reinterpret_cast<const bf16x8*>(&Ps[wave][l15][ks * 32 + 8 * lhi]);
#pragma unroll
                for (int nf = 0; nf < 8; ++nf) {
                    int row = nf * 16 + l15;
                    bf16x8 vb = *reinterpret_cast<const bf16x8*>(
                        (const char*)Vs[cur] + ((row * 128 + (ks * 4 + lhi) * 16) ^ ((row & 7) << 4)));
                    oacc[nf] = __builtin_amdgcn_mfma_f32_16x16x32_bf16(pa, vb, oacc[nf], 0, 0, 0);
                }
            }

            if (pre) {
#pragma unroll
                for (int i = 0; i < 4; ++i) {
                    int id = tid + i * 256;
                    int krow = id >> 4, kc = id & 15;
                    *reinterpret_cast<bf16x8*>((char*)Ks[cur ^ 1] + ((krow * 256 + kc * 16) ^ ((krow & 7) << 4))) = kr[i];
                    int vrow = id >> 3, vc = id & 7;
                    *reinterpret_cast<bf16x8*>((char*)Vs[cur ^ 1] + ((vrow * 128 + vc * 16) ^ ((vrow & 7) << 4))) = vr[i];
                }
            }
            __syncthreads();
        }

#pragma unroll
        for (int m = 1; m < 16; m <<= 1)
#pragma unroll
            for (int r = 0; r < 4; ++r)
                Lp[r] += __shfl_xor(Lp[r], m);
        float inv[4];
#pragma unroll
        for (int r = 0; r < 4; ++r) inv[r] = 1.f / Lp[r];
#pragma unroll
        for (int nf = 0; nf < 8; ++nf)
#pragma unroll
            for (int r = 0; r < 4; ++r) {
                int s = qw + lhi * 4 + r;
                int d = nf * 16 + l15;
                Ob[((size_t)(b * SS + s)) * HH + h * HD + d] = (bf16)(oacc[nf][r] * inv[r]);
            }
    }
}

// ---------------------------------------------------------------------------
extern "C" void kernel_launch(void* const* d_in, const int* in_sizes, int n_in,
                              void* d_out, int out_size, void* d_ws, size_t ws_size,
                              hipStream_t stream) {
    const float* hs   = (const float*)d_in[0];
    const float* cosT = (const float*)d_in[2];
    const float* sinT = (const float*)d_in[3];
    const float* Wq   = (const float*)d_in[4];
    const float* Wk   = (const float*)d_in[5];
    const float* Wv   = (const float*)d_in[6];
    const float* Wo   = (const float*)d_in[7];
    float* out = (float*)d_out;

    char* w = (char*)d_ws;
    auto alloc = [&](size_t bytes) {
        char* p = w;
        w += (bytes + 255) & ~(size_t)255;
        return p;
    };
    const size_t XE = (size_t)BB * SS * HH;
    const size_t WE = (size_t)HH * HH;
    bf16* Xb   = (bf16*)alloc(XE * 2);
    bf16* Wqkv = (bf16*)alloc(3 * WE * 2);
    bf16* Wob  = (bf16*)alloc(WE * 2);
    bf16* QKV  = (bf16*)alloc(3 * XE * 2);
    bf16* Vtg  = (bf16*)alloc(XE * 2);
    bf16* Ob   = (bf16*)alloc(XE * 2);

    const int M = BB * SS;  // 4096
    bf16* Qh = QKV;
    bf16* Kh = QKV + XE;
    bf16* Vh = QKV + 2 * XE;

    cast_f32_bf16<<<(int)(XE / 4 + 255) / 256, 256, 0, stream>>>(hs, Xb, (int)(XE / 4));
    cast_f32_bf16<<<(int)(WE / 4 + 255) / 256, 256, 0, stream>>>(Wq, Wqkv, (int)(WE / 4));
    cast_f32_bf16<<<(int)(WE / 4 + 255) / 256, 256, 0, stream>>>(Wk, Wqkv + WE, (int)(WE / 4));
    cast_f32_bf16<<<(int)(WE / 4 + 255) / 256, 256, 0, stream>>>(Wv, Wqkv + 2 * WE, (int)(WE / 4));
    cast_f32_bf16<<<(int)(WE / 4 + 255) / 256, 256, 0, stream>>>(Wo, Wob, (int)(WE / 4));

    // fused QKV projection: M=4096, N=6144, K=2048, 256^2 8-phase
    gemm256_qkv<<<dim3((M / 256) * (3 * HH / 256)), 512, 0, stream>>>(Xb, Wqkv, QKV, M, 3 * HH, HH);

    rope_kernel<<<(BB * NH * SS * 8) / 256, 256, 0, stream>>>(Qh, Kh, cosT, sinT);

    dim3 tgrid(SS / 64, HD / 64, BB * NH);
    transpose_v<<<tgrid, 256, 0, stream>>>(Vh, Vtg);

    attn_kernel<<<512, 256, 0, stream>>>(Qh, Kh, Vtg, Ob);

    dim3 ogrid(HH / 128, M / 128);
    gemm_bt<<<ogrid, 256, 0, stream>>>(Ob, Wob, out, M, HH, HH);
}

// Round 5
// 301.714 us; speedup vs baseline: 1.0875x; 1.0610x over previous
//
#include <hip/hip_runtime.h>
#include <hip/hip_bf16.h>

typedef __bf16 bf16;
typedef __attribute__((ext_vector_type(8))) __bf16 bf16x8;
typedef __attribute__((ext_vector_type(4))) __bf16 bf16x4;
typedef __attribute__((ext_vector_type(4))) float f32x4;

// Problem constants
#define BB 2
#define SS 2048
#define HH 2048
#define NH 16
#define HD 128

#define GLOAD_LDS16(g, l)                                                  \
    __builtin_amdgcn_global_load_lds(                                      \
        (const __attribute__((address_space(1))) void*)(g),                \
        (__attribute__((address_space(3))) void*)(l), 16, 0, 0)

// ---------------------------------------------------------------------------
// Batched fp32 -> bf16 cast: X (XE) then Wq,Wk,Wv (into contiguous Wqkv), Wo.
// One launch. 4 elements/thread, segment-dispatched.
// ---------------------------------------------------------------------------
__global__ __launch_bounds__(256) void cast_all(const float* __restrict__ hs,
                                                const float* __restrict__ Wq,
                                                const float* __restrict__ Wk,
                                                const float* __restrict__ Wv,
                                                const float* __restrict__ Wo,
                                                bf16* __restrict__ Xb,
                                                bf16* __restrict__ Wqkv,
                                                bf16* __restrict__ Wob) {
    const int XE4 = (BB * SS * HH) / 4;      // 2097152
    const int WE4 = (HH * HH) / 4;           // 1048576
    int i = blockIdx.x * 256 + threadIdx.x;
    const float* src;
    bf16* dst;
    int off;
    if (i < XE4) { src = hs; dst = Xb; off = i; }
    else if (i < XE4 + WE4) { src = Wq; dst = Wqkv; off = i - XE4; }
    else if (i < XE4 + 2 * WE4) { src = Wk; dst = Wqkv + (size_t)HH * HH; off = i - XE4 - WE4; }
    else if (i < XE4 + 3 * WE4) { src = Wv; dst = Wqkv + 2 * (size_t)HH * HH; off = i - XE4 - 2 * WE4; }
    else { src = Wo; dst = Wob; off = i - XE4 - 3 * WE4; }
    f32x4 v = *reinterpret_cast<const f32x4*>(src + (size_t)off * 4);
    bf16x4 o;
    o[0] = (bf16)v[0]; o[1] = (bf16)v[1]; o[2] = (bf16)v[2]; o[3] = (bf16)v[3];
    *reinterpret_cast<bf16x4*>(dst + (size_t)off * 4) = o;
}

// ---------------------------------------------------------------------------
// 256x256-tile 8-phase GEMM (T2+T3+T4+T5), QKV epilogue.
// C[m,n] = sum_k A[m,k]*B[n,k]. 512 threads = 8 waves (2 wr x 4 wc).
// Per wave: 128x64 output = acc[8][4]. BK=64, 2-K-tile LDS double buffer.
// 3-bit swizzle (m214 recipe): byte ^= ((byte>>7)&7)<<4 — optimal 8x8 bank
// spread for 16-consecutive-row ds_read_b128. Both-sides: pre-swizzled
// global src (linear gload_lds dest) + swizzled ds_read (rule #21).
// Staging stream at tile t: q0->B0(t+1) q1->A1(t+1) q2->A0(t+2) q3->B1(t+2);
// boundary s_waitcnt vmcnt(4); vmcnt(0) only before the last K-tile.
// ---------------------------------------------------------------------------
__global__ __launch_bounds__(512, 2) void gemm256_qkv(const bf16* __restrict__ A,
                                                      const bf16* __restrict__ B,
                                                      bf16* __restrict__ Cb,
                                                      int M, int N, int K) {
    __shared__ bf16 LA[2][256 * 64];
    __shared__ bf16 LB[2][256 * 64];
    const int tid = threadIdx.x, lane = tid & 63, wave = tid >> 6;
    const int l15 = lane & 15, lhi = lane >> 4;
    const int wr = wave >> 2, wc = wave & 3;
    const int NBX = N >> 8;
    const int cpx = gridDim.x >> 3;                        // nwg % 8 == 0
    const int wg = (blockIdx.x & 7) * cpx + (blockIdx.x >> 3);
    const int m0 = (wg / NBX) * 256, n0 = (wg % NBX) * 256;
    const int NK = K >> 6;
    const int xorR = (l15 & 7) << 4;                       // read-side swizzle

    // stage A half h (rows [h*64,h*64+64) U [128+h*64,...)) of K-tile t
    auto stageA = [&](int buf, int t, int h) {
        const int k0 = t << 6;
#pragma unroll
        for (int j = 0; j < 2; ++j) {
            int Xw = ((j * 128 + h * 64) << 7) + (wave << 10);   // wave-uniform LDS byte
            int X = Xw + lane * 16;
            int T = X ^ (((X >> 7) & 7) << 4);                   // inverse-swizzled source
            GLOAD_LDS16(&A[(size_t)(m0 + (T >> 7)) * K + k0 + ((T & 127) >> 1)],
                        (char*)LA[buf] + Xw);
        }
    };
    // stage B half h (rows with bit5==h) of K-tile t
    auto stageB = [&](int buf, int t, int h) {
        const int k0 = t << 6;
#pragma unroll
        for (int j = 0; j < 2; ++j) {
            int base_row = h * 32 + (2 * j + (wave >> 2)) * 64;
            int Xw = (base_row << 7) + ((wave & 3) << 10);
            int X = Xw + lane * 16;
            int T = X ^ (((X >> 7) & 7) << 4);
            GLOAD_LDS16(&B[(size_t)(n0 + (T >> 7)) * K + k0 + ((T & 127) >> 1)],
                        (char*)LB[buf] + Xw);
        }
    };

    f32x4 acc[8][4] = {};

    // prologue: tile0 all 4 halves + A0(1), B1(1)
    stageA(0, 0, 0); stageB(0, 0, 0); stageB(0, 0, 1); stageA(0, 0, 1);
    stageA(1, 1, 0); stageB(1, 1, 1);
    asm volatile("s_waitcnt vmcnt(4)" ::: "memory");       // tile0 landed
    __builtin_amdgcn_s_barrier();

    bf16x8 af[4][2], bv0[2][2], bv1[2][2];

#pragma unroll 1
    for (int t = 0; t < NK; ++t) {
        const int buf = t & 1;
        char* lA = (char*)LA[buf];
        char* lB = (char*)LB[buf];

        // ===== phase q0: quadrant (0,0); read A0(8)+B0(4); stage B0(t+1)
#pragma unroll
        for (int f = 0; f < 4; ++f)
#pragma unroll
            for (int ks = 0; ks < 2; ++ks) {
                int T = ((wr * 128 + f * 16 + l15) << 7) + ks * 64 + lhi * 16;
                af[f][ks] = *reinterpret_cast<const bf16x8*>(lA + (T ^ xorR));
            }
#pragma unroll
        for (int g = 0; g < 2; ++g)
#pragma unroll
            for (int ks = 0; ks < 2; ++ks) {
                int T = ((wc * 64 + g * 16 + l15) << 7) + ks * 64 + lhi * 16;
                bv0[g][ks] = *reinterpret_cast<const bf16x8*>(lB + (T ^ xorR));
            }
        if (t + 1 < NK) stageB(buf ^ 1, t + 1, 0);
        __builtin_amdgcn_s_barrier();
        asm volatile("s_waitcnt lgkmcnt(0)" ::: "memory");
        __builtin_amdgcn_s_setprio(1);
#pragma unroll
        for (int f = 0; f < 4; ++f)
#pragma unroll
            for (int g = 0; g < 2; ++g)
#pragma unroll
                for (int ks = 0; ks < 2; ++ks)
                    acc[f][g] = __builtin_amdgcn_mfma_f32_16x16x32_bf16(af[f][ks], bv0[g][ks], acc[f][g], 0, 0, 0);
        __builtin_amdgcn_s_setprio(0);
        __builtin_amdgcn_s_barrier();

        // ===== phase q1: quadrant (0,1); read B1(4); reuse af; stage A1(t+1)
#pragma unroll
        for (int g = 0; g < 2; ++g)
#pragma unroll
            for (int ks = 0; ks < 2; ++ks) {
                int T = ((wc * 64 + 32 + g * 16 + l15) << 7) + ks * 64 + lhi * 16;
                bv1[g][ks] = *reinterpret_cast<const bf16x8*>(lB + (T ^ xorR));
            }
        if (t + 1 < NK) stageA(buf ^ 1, t + 1, 1);
        __builtin_amdgcn_s_barrier();
        asm volatile("s_waitcnt lgkmcnt(0)" ::: "memory");
        __builtin_amdgcn_s_setprio(1);
#pragma unroll
        for (int f = 0; f < 4; ++f)
#pragma unroll
            for (int g = 0; g < 2; ++g)
#pragma unroll
                for (int ks = 0; ks < 2; ++ks)
                    acc[f][2 + g] = __builtin_amdgcn_mfma_f32_16x16x32_bf16(af[f][ks], bv1[g][ks], acc[f][2 + g], 0, 0, 0);
        __builtin_amdgcn_s_setprio(0);
        __builtin_amdgcn_s_barrier();

        // ===== phase q2: quadrant (1,1); read A1(8); reuse bv1; stage A0(t+2)
#pragma unroll
        for (int f = 0; f < 4; ++f)
#pragma unroll
            for (int ks = 0; ks < 2; ++ks) {
                int T = ((wr * 128 + 64 + f * 16 + l15) << 7) + ks * 64 + lhi * 16;
                af[f][ks] = *reinterpret_cast<const bf16x8*>(lA + (T ^ xorR));
            }
        if (t + 2 < NK) stageA(buf, t + 2, 0);
        __builtin_amdgcn_s_barrier();
        asm volatile("s_waitcnt lgkmcnt(0)" ::: "memory");
        __builtin_amdgcn_s_setprio(1);
#pragma unroll
        for (int f = 0; f < 4; ++f)
#pragma unroll
            for (int g = 0; g < 2; ++g)
#pragma unroll
                for (int ks = 0; ks < 2; ++ks)
                    acc[4 + f][2 + g] = __builtin_amdgcn_mfma_f32_16x16x32_bf16(af[f][ks], bv1[g][ks], acc[4 + f][2 + g], 0, 0, 0);
        __builtin_amdgcn_s_setprio(0);
        __builtin_amdgcn_s_barrier();

        // ===== phase q3: quadrant (1,0); no reads; stage B1(t+2)
        if (t + 2 < NK) stageB(buf, t + 2, 1);
        __builtin_amdgcn_s_barrier();
        __builtin_amdgcn_s_setprio(1);
#pragma unroll
        for (int f = 0; f < 4; ++f)
#pragma unroll
            for (int g = 0; g < 2; ++g)
#pragma unroll
                for (int ks = 0; ks < 2; ++ks)
                    acc[4 + f][g] = __builtin_amdgcn_mfma_f32_16x16x32_bf16(af[f][ks], bv0[g][ks], acc[4 + f][g], 0, 0, 0);
        __builtin_amdgcn_s_setprio(0);
        if (t + 2 == NK) {
            asm volatile("s_waitcnt vmcnt(0)" ::: "memory");
        } else if (t + 1 < NK) {
            asm volatile("s_waitcnt vmcnt(4)" ::: "memory");
        }
        __builtin_amdgcn_s_barrier();
    }

    // epilogue: per-head scatter [proj][b*NH+h][s][d] bf16
#pragma unroll
    for (int mf = 0; mf < 8; ++mf)
#pragma unroll
        for (int nf = 0; nf < 4; ++nf)
#pragma unroll
            for (int r = 0; r < 4; ++r) {
                int gm = m0 + wr * 128 + mf * 16 + lhi * 4 + r;
                int gn = n0 + wc * 64 + nf * 16 + l15;
                int proj = gn >> 11, n2 = gn & 2047;
                int b = gm >> 11, s = gm & (SS - 1);
                int h = n2 >> 7, d = n2 & (HD - 1);
                Cb[((size_t)proj << 23) + ((((size_t)(b * NH + h)) * SS + s) << 7) + d] =
                    (bf16)acc[mf][nf][r];
            }
}

// ---------------------------------------------------------------------------
// 128x128 GEMM (m97 structure), fp32 row-major epilogue (out projection)
// ---------------------------------------------------------------------------
__global__ __launch_bounds__(256) void gemm_bt(const bf16* __restrict__ A,
                                               const bf16* __restrict__ B,
                                               float* __restrict__ Cf,
                                               int M, int N, int K) {
    __shared__ bf16 As[128 * 64];
    __shared__ bf16 Bs[128 * 64];
    const int tid = threadIdx.x;
    const int lane = tid & 63, wave = tid >> 6;
    const int l15 = lane & 15, lhi = lane >> 4;
    const int m0 = blockIdx.y * 128, n0 = blockIdx.x * 128;
    const int wm = (wave >> 1) * 64, wn = (wave & 1) * 64;
    const int lrow = lane >> 3;
    const int lcol = (lane & 7) * 8;

    f32x4 acc[4][4] = {};

    for (int k0 = 0; k0 < K; k0 += 64) {
#pragma unroll
        for (int j = 0; j < 4; ++j) {
            const int c = wave * 4 + j;
            const int row = c * 8 + lrow;
            GLOAD_LDS16(&A[(size_t)(m0 + row) * K + k0 + lcol], &As[c * 512]);
            GLOAD_LDS16(&B[(size_t)(n0 + row) * K + k0 + lcol], &Bs[c * 512]);
        }
        __syncthreads();
#pragma unroll
        for (int ks = 0; ks < 2; ++ks) {
            bf16x8 af[4], bfr[4];
#pragma unroll
            for (int i = 0; i < 4; ++i)
                af[i] = *reinterpret_cast<const bf16x8*>(&As[(wm + i * 16 + l15) * 64 + ks * 32 + 8 * lhi]);
#pragma unroll
            for (int j = 0; j < 4; ++j)
                bfr[j] = *reinterpret_cast<const bf16x8*>(&Bs[(wn + j * 16 + l15) * 64 + ks * 32 + 8 * lhi]);
#pragma unroll
            for (int i = 0; i < 4; ++i)
#pragma unroll
                for (int j = 0; j < 4; ++j)
                    acc[i][j] = __builtin_amdgcn_mfma_f32_16x16x32_bf16(af[i], bfr[j], acc[i][j], 0, 0, 0);
        }
        __syncthreads();
    }

#pragma unroll
    for (int i = 0; i < 4; ++i)
#pragma unroll
        for (int j = 0; j < 4; ++j)
#pragma unroll
            for (int r = 0; r < 4; ++r) {
                int gm = m0 + wm + i * 16 + lhi * 4 + r;
                int gn = n0 + wn + j * 16 + l15;
                Cf[(size_t)gm * N + gn] = acc[i][j][r];
            }
}

// ---------------------------------------------------------------------------
// Transpose V per head: Vh[head][s][d] -> Vt[head][d][s]
// ---------------------------------------------------------------------------
__global__ __launch_bounds__(256) void transpose_v(const bf16* __restrict__ Vh,
                                                   bf16* __restrict__ Vt) {
    __shared__ bf16 T[64 * 64];
    const int tid = threadIdx.x;
    const int s0 = blockIdx.x * 64, d0 = blockIdx.y * 64, head = blockIdx.z;
    const bf16* src = Vh + ((size_t)head * SS) * HD;
    bf16* dst = Vt + ((size_t)head * HD) * SS;

#pragma unroll
    for (int i = 0; i < 2; ++i) {
        int id = tid + i * 256;
        int r = id >> 3, c16 = id & 7;
        bf16x8 v = *reinterpret_cast<const bf16x8*>(&src[(size_t)(s0 + r) * HD + d0 + c16 * 8]);
        int sw = c16 ^ ((r ^ (r >> 3)) & 7);
        *reinterpret_cast<bf16x8*>((char*)T + r * 128 + sw * 16) = v;
    }
    __syncthreads();
#pragma unroll
    for (int i = 0; i < 2; ++i) {
        int id = tid + i * 256;
        int dr = id >> 3, sc8 = (id & 7) * 8;
        bf16x8 o;
#pragma unroll
        for (int j = 0; j < 8; ++j) {
            int r = sc8 + j;
            int sw = (dr >> 3) ^ ((r ^ (r >> 3)) & 7);
            o[j] = *reinterpret_cast<const bf16*>((char*)T + r * 128 + sw * 16 + (dr & 7) * 2);
        }
        *reinterpret_cast<bf16x8*>(&dst[(size_t)(d0 + dr) * SS + s0 + sc8]) = o;
    }
}

// ---------------------------------------------------------------------------
// RoPE (rotate_half), vectorized
// ---------------------------------------------------------------------------
__global__ __launch_bounds__(256) void rope_kernel(bf16* __restrict__ Qh, bf16* __restrict__ Kh,
                                                   const float* __restrict__ cosT,
                                                   const float* __restrict__ sinT) {
    int idx = blockIdx.x * 256 + threadIdx.x;
    int g = idx & 7;
    int s = (idx >> 3) & (SS - 1);
    int head = idx >> 14;
    int d0 = g * 8;
    size_t base = ((size_t)head * SS + s) * HD;
    f32x4 ca = *reinterpret_cast<const f32x4*>(&cosT[s * HD + d0]);
    f32x4 cb = *reinterpret_cast<const f32x4*>(&cosT[s * HD + d0 + 4]);
    f32x4 sa = *reinterpret_cast<const f32x4*>(&sinT[s * HD + d0]);
    f32x4 sb = *reinterpret_cast<const f32x4*>(&sinT[s * HD + d0 + 4]);
    bf16x8 ql = *reinterpret_cast<const bf16x8*>(&Qh[base + d0]);
    bf16x8 qh = *reinterpret_cast<const bf16x8*>(&Qh[base + 64 + d0]);
    bf16x8 kl = *reinterpret_cast<const bf16x8*>(&Kh[base + d0]);
    bf16x8 kh = *reinterpret_cast<const bf16x8*>(&Kh[base + 64 + d0]);
    bf16x8 qlo, qhi, klo, khi;
#pragma unroll
    for (int j = 0; j < 8; ++j) {
        float c = (j < 4) ? ca[j] : cb[j - 4];
        float sn = (j < 4) ? sa[j] : sb[j - 4];
        float q0 = (float)ql[j], q1 = (float)qh[j];
        float k0 = (float)kl[j], k1 = (float)kh[j];
        qlo[j] = (bf16)(q0 * c - q1 * sn);
        qhi[j] = (bf16)(q1 * c + q0 * sn);
        klo[j] = (bf16)(k0 * c - k1 * sn);
        khi[j] = (bf16)(k1 * c + k0 * sn);
    }
    *reinterpret_cast<bf16x8*>(&Qh[base + d0]) = qlo;
    *reinterpret_cast<bf16x8*>(&Qh[base + 64 + d0]) = qhi;
    *reinterpret_cast<bf16x8*>(&Kh[base + d0]) = klo;
    *reinterpret_cast<bf16x8*>(&Kh[base + 64 + d0]) = khi;
}

// ---------------------------------------------------------------------------
// Causal flash attention, load-balanced, K/V double-buffered, XOR-swizzled LDS,
// defer-max softmax. grid = 512, block = 256 (4 waves x 16 q-rows, QB=64).
// ---------------------------------------------------------------------------
__global__ __launch_bounds__(256) void attn_kernel(const bf16* __restrict__ Q,
                                                   const bf16* __restrict__ K,
                                                   const bf16* __restrict__ Vt,
                                                   bf16* __restrict__ Ob) {
    __shared__ bf16 Ks[2][64 * 128];
    __shared__ bf16 Vs[2][128 * 64];
    __shared__ bf16 Ps[4][16][72];

    const int tid = threadIdx.x, lane = tid & 63, wave = tid >> 6;
    const int l15 = lane & 15, lhi = lane >> 4;
    const int bid = blockIdx.x;
    const int orig = (bid & 7) * 64 + (bid >> 3);
    const int head = orig >> 4;
    const int pi = orig & 15;
    const int b = head >> 4, h = head & (NH - 1);
    const size_t hb = (size_t)head * SS * HD;
    const bf16* Vth = Vt + (size_t)head * HD * SS;
    const float cexp = 0.08838834764831845f * 1.4426950408889634f;
    const float THR = 62.0f;

#pragma unroll 1
    for (int part = 0; part < 2; ++part) {
        const int t = part ? (31 - pi) : pi;
        const int q0 = t * 64;
        const int qw = q0 + wave * 16;
        const int nkv = t + 1;

        bf16x8 qf[4];
#pragma unroll
        for (int ks = 0; ks < 4; ++ks)
            qf[ks] = *reinterpret_cast<const bf16x8*>(
                &Q[hb + (size_t)(qw + l15) * HD + ks * 32 + 8 * lhi]);

        f32x4 oacc[8] = {};
        float Mr[4], Lp[4];
#pragma unroll
        for (int r = 0; r < 4; ++r) { Mr[r] = -INFINITY; Lp[r] = 0.f; }

        bf16x8 kr[4], vr[4];
#pragma unroll
        for (int i = 0; i < 4; ++i) {
            int id = tid + i * 256;
            kr[i] = *reinterpret_cast<const bf16x8*>(&K[hb + (size_t)(id >> 4) * HD + (id & 15) * 8]);
            vr[i] = *reinterpret_cast<const bf16x8*>(&Vth[(size_t)(id >> 3) * SS + (id & 7) * 8]);
        }
#pragma unroll
        for (int i = 0; i < 4; ++i) {
            int id = tid + i * 256;
            int krow = id >> 4, kc = id & 15;
            *reinterpret_cast<bf16x8*>((char*)Ks[0] + ((krow * 256 + kc * 16) ^ ((krow & 7) << 4))) = kr[i];
            int vrow = id >> 3, vc = id & 7;
            *reinterpret_cast<bf16x8*>((char*)Vs[0] + ((vrow * 128 + vc * 16) ^ ((vrow & 7) << 4))) = vr[i];
        }
        __syncthreads();

        for (int it = 0; it < nkv; ++it) {
            const int cur = it & 1;
            const bool pre = (it + 1 < nkv);
            if (pre) {
                const int kv0 = (it + 1) * 64;
#pragma unroll
                for (int i = 0; i < 4; ++i) {
                    int id = tid + i * 256;
                    kr[i] = *reinterpret_cast<const bf16x8*>(&K[hb + (size_t)(kv0 + (id >> 4)) * HD + (id & 15) * 8]);
                    vr[i] = *reinterpret_cast<const bf16x8*>(&Vth[(size_t)(id >> 3) * SS + kv0 + (id & 7) * 8]);
                }
            }

            f32x4 sf[4] = {};
#pragma unroll
            for (int ks = 0; ks < 4; ++ks) {
#pragma unroll
                for (int ne = 0; ne < 4; ++ne) {
                    int row = ne * 16 + l15;
                    bf16x8 kf = *reinterpret_cast<const bf16x8*>(
                        (const char*)Ks[cur] + ((row * 256 + (ks * 4 + lhi) * 16) ^ ((row & 7) << 4)));
                    sf[ne] = __builtin_amdgcn_mfma_f32_16x16x32_bf16(qf[ks], kf, sf[ne], 0, 0, 0);
                }
            }

            if (it == nkv - 1) {
#pragma unroll
                for (int ne = 0; ne < 4; ++ne)
#pragma unroll
                    for (int r = 0; r < 4; ++r) {
                        int gq = qw + lhi * 4 + r;
                        int gk = it * 64 + ne * 16 + l15;
                        if (gk > gq) sf[ne][r] = -INFINITY;
                    }
            }

            float lm[4];
#pragma unroll
            for (int r = 0; r < 4; ++r)
                lm[r] = fmaxf(fmaxf(sf[0][r], sf[1][r]), fmaxf(sf[2][r], sf[3][r]));
            bool need = (lm[0] > Mr[0] + THR) || (lm[1] > Mr[1] + THR) ||
                        (lm[2] > Mr[2] + THR) || (lm[3] > Mr[3] + THR);
            if (__any(need)) {
                float rmax[4] = {lm[0], lm[1], lm[2], lm[3]};
#pragma unroll
                for (int m = 1; m < 16; m <<= 1)
#pragma unroll
                    for (int r = 0; r < 4; ++r)
                        rmax[r] = fmaxf(rmax[r], __shfl_xor(rmax[r], m));
#pragma unroll
                for (int r = 0; r < 4; ++r) {
                    float nM = fmaxf(Mr[r], rmax[r]);
                    float scf = __builtin_amdgcn_exp2f((Mr[r] - nM) * cexp);
                    Mr[r] = nM;
                    Lp[r] *= scf;
#pragma unroll
                    for (int nf = 0; nf < 8; ++nf) oacc[nf][r] *= scf;
                }
            }
#pragma unroll
            for (int ne = 0; ne < 4; ++ne)
#pragma unroll
                for (int r = 0; r < 4; ++r) {
                    float p = __builtin_amdgcn_exp2f((sf[ne][r] - Mr[r]) * cexp);
                    Lp[r] += p;
                    Ps[wave][lhi * 4 + r][ne * 16 + l15] = (bf16)p;
                }

#pragma unroll
            for (int ks = 0; ks < 2; ++ks) {
                bf16x8 pa = *reinterpret_cast<const bf16x8*>(&Ps[wave][l15][ks * 32 + 8 * lhi]);
#pragma unroll
                for (int nf = 0; nf < 8; ++nf) {
                    int row = nf * 16 + l15;
                    bf16x8 vb = *reinterpret_cast<const bf16x8*>(
                        (const char*)Vs[cur] + ((row * 128 + (ks * 4 + lhi) * 16) ^ ((row & 7) << 4)));
                    oacc[nf] = __builtin_amdgcn_mfma_f32_16x16x32_bf16(pa, vb, oacc[nf], 0, 0, 0);
                }
            }

            if (pre) {
#pragma unroll
                for (int i = 0; i < 4; ++i) {
                    int id = tid + i * 256;
                    int krow = id >> 4, kc = id & 15;
                    *reinterpret_cast<bf16x8*>((char*)Ks[cur ^ 1] + ((krow * 256 + kc * 16) ^ ((krow & 7) << 4))) = kr[i];
                    int vrow = id >> 3, vc = id & 7;
                    *reinterpret_cast<bf16x8*>((char*)Vs[cur ^ 1] + ((vrow * 128 + vc * 16) ^ ((vrow & 7) << 4))) = vr[i];
                }
            }
            __syncthreads();
        }

#pragma unroll
        for (int m = 1; m < 16; m <<= 1)
#pragma unroll
            for (int r = 0; r < 4; ++r)
                Lp[r] += __shfl_xor(Lp[r], m);
        float inv[4];
#pragma unroll
        for (int r = 0; r < 4; ++r) inv[r] = 1.f / Lp[r];
#pragma unroll
        for (int nf = 0; nf < 8; ++nf)
#pragma unroll
            for (int r = 0; r < 4; ++r) {
                int s = qw + lhi * 4 + r;
                int d = nf * 16 + l15;
                Ob[((size_t)(b * SS + s)) * HH + h * HD + d] = (bf16)(oacc[nf][r] * inv[r]);
            }
    }
}

// ---------------------------------------------------------------------------
extern "C" void kernel_launch(void* const* d_in, const int* in_sizes, int n_in,
                              void* d_out, int out_size, void* d_ws, size_t ws_size,
                              hipStream_t stream) {
    const float* hs   = (const float*)d_in[0];
    const float* cosT = (const float*)d_in[2];
    const float* sinT = (const float*)d_in[3];
    const float* Wq   = (const float*)d_in[4];
    const float* Wk   = (const float*)d_in[5];
    const float* Wv   = (const float*)d_in[6];
    const float* Wo   = (const float*)d_in[7];
    float* out = (float*)d_out;

    char* w = (char*)d_ws;
    auto alloc = [&](size_t bytes) {
        char* p = w;
        w += (bytes + 255) & ~(size_t)255;
        return p;
    };
    const size_t XE = (size_t)BB * SS * HH;
    const size_t WE = (size_t)HH * HH;
    bf16* Xb   = (bf16*)alloc(XE * 2);
    bf16* Wqkv = (bf16*)alloc(3 * WE * 2);
    bf16* Wob  = (bf16*)alloc(WE * 2);
    bf16* QKV  = (bf16*)alloc(3 * XE * 2);
    bf16* Vtg  = (bf16*)alloc(XE * 2);
    bf16* Ob   = (bf16*)alloc(XE * 2);

    const int M = BB * SS;  // 4096
    bf16* Qh = QKV;
    bf16* Kh = QKV + XE;
    bf16* Vh = QKV + 2 * XE;

    // one batched cast launch: X + Wq + Wk + Wv + Wo
    {
        int total4 = (int)((XE + 4 * WE) / 4);
        cast_all<<<(total4 + 255) / 256, 256, 0, stream>>>(hs, Wq, Wk, Wv, Wo, Xb, Wqkv, Wob);
    }

    // fused QKV projection: M=4096, N=6144, K=2048, 256^2 8-phase
    gemm256_qkv<<<dim3((M / 256) * (3 * HH / 256)), 512, 0, stream>>>(Xb, Wqkv, QKV, M, 3 * HH, HH);

    rope_kernel<<<(BB * NH * SS * 8) / 256, 256, 0, stream>>>(Qh, Kh, cosT, sinT);

    dim3 tgrid(SS / 64, HD / 64, BB * NH);
    transpose_v<<<tgrid, 256, 0, stream>>>(Vh, Vtg);

    attn_kernel<<<512, 256, 0, stream>>>(Qh, Kh, Vtg, Ob);

    dim3 ogrid(HH / 128, M / 128);
    gemm_bt<<<ogrid, 256, 0, stream>>>(Ob, Wob, out, M, HH, HH);
}